// Round 7
// baseline (131.965 us; speedup 1.0000x reference)
//
#include <hip/hip_runtime.h>
#include <hip/hip_bf16.h>
#include <stdint.h>

typedef short s16x8 __attribute__((ext_vector_type(8)));
typedef float f32x4 __attribute__((ext_vector_type(4)));

static constexpr int DDIM = 256;
static constexpr float TEN_LOG2E = 14.4269504088896340736f; // 10 * log2(e)

__device__ __forceinline__ float bf2f(ushort u) {
    return __builtin_bit_cast(float, (uint32_t)u << 16);
}

// ---------------- Kernel 1: normalize + pack into MFMA-fragment order ----------------
// 512 blocks x 256 threads; block g handles rows [16g, 16g+16). packed layout:
// packed[((g*8 + kt)*64 + lane)*8 .. +8] = bf16 P[16g + (lane&15)][kt*32 + (lane>>4)*8 ..]
// Each (group, kt) fragment is a contiguous 1KB block in exact lane order.
// Also zero-inits row_s[8192] (blocks 0..7) and out[0] (block 0).
__global__ __launch_bounds__(256) void normalize_pack_kernel(
    const float* __restrict__ zi, const float* __restrict__ zj,
    ushort* __restrict__ packed, float* __restrict__ row_s, float* __restrict__ out)
{
    __shared__ ushort lds[16 * 256];

    if (blockIdx.x < 8) {
        ((float4*)row_s)[blockIdx.x * 256 + threadIdx.x] = (float4){0.f, 0.f, 0.f, 0.f};
        if (blockIdx.x == 0 && threadIdx.x == 0) out[0] = 0.0f;
    }

    const int t = threadIdx.x;
    const int r = t >> 4;            // 0..15: row within group
    const int c = t & 15;            // 16 threads per row
    const int row = blockIdx.x * 16 + r;
    const float* src = (row < 4096) ? (zi + (size_t)row * DDIM)
                                    : (zj + (size_t)(row - 4096) * DDIM);
    float4 v[4];
    #pragma unroll
    for (int j = 0; j < 4; ++j) v[j] = ((const float4*)src)[c + j * 16];

    float ss = 0.0f;
    #pragma unroll
    for (int j = 0; j < 4; ++j)
        ss += v[j].x * v[j].x + v[j].y * v[j].y + v[j].z * v[j].z + v[j].w * v[j].w;
    ss += __shfl_xor(ss, 1, 64);
    ss += __shfl_xor(ss, 2, 64);
    ss += __shfl_xor(ss, 4, 64);
    ss += __shfl_xor(ss, 8, 64);
    const float inv = 1.0f / fmaxf(sqrtf(ss), 1e-8f);

    #pragma unroll
    for (int j = 0; j < 4; ++j) {
        ushort4 o;
        o.x = __builtin_bit_cast(unsigned short, __float2bfloat16(v[j].x * inv));
        o.y = __builtin_bit_cast(unsigned short, __float2bfloat16(v[j].y * inv));
        o.z = __builtin_bit_cast(unsigned short, __float2bfloat16(v[j].z * inv));
        o.w = __builtin_bit_cast(unsigned short, __float2bfloat16(v[j].w * inv));
        *(ushort4*)(lds + r * 256 + (c + j * 16) * 4) = o;
    }
    __syncthreads();

    #pragma unroll
    for (int h = 0; h < 2; ++h) {
        const int idx  = h * 256 + t;
        const int kt   = idx >> 6;
        const int lane = idx & 63;
        const int q    = lane >> 4;
        const int l15  = lane & 15;
        s16x8 frag = *(const s16x8*)(lds + l15 * 256 + kt * 32 + q * 8);
        ((s16x8*)packed)[(size_t)(blockIdx.x * 8 + kt) * 64 + lane] = frag;
    }
}

// ---------------- Kernel 2: j-strips of 4 tiles, register-carried row sums -----------
// Grid (16, 64): ti = blockIdx.y, strip tj0 = ti + 4*blockIdx.x. Empty strips return.
// 4 waves, each a 64x64 sub-tile (16x16x32 MFMA, 4x4 frags) per tile. rsum carried in
// registers across the 4 tiles (atomics once/block); csum batched per tile at the end.
// No LDS/barriers; fragments are contiguous 1KB coalesced loads from packed.
__global__ __launch_bounds__(256) void simexp_kernel(
    const ushort* __restrict__ packed,
    float* __restrict__ row_s)
{
    const int tid  = threadIdx.x;
    const int w    = tid >> 6;
    const int lane = tid & 63;
    const int q    = lane >> 4;
    const int l15  = lane & 15;
    const int wm   = (w >> 1) * 64;
    const int wn   = (w & 1) * 64;

    const int ti  = blockIdx.y;
    const int tj0 = ti + blockIdx.x * 4;
    if (tj0 >= 64) return;
    const int r0 = ti * 128;

    const int gA = (r0 + wm) >> 4;
    const ushort* pa[4];
    #pragma unroll
    for (int mi = 0; mi < 4; ++mi)
        pa[mi] = packed + (size_t)(gA + mi) * 4096 + (size_t)lane * 8;

    float rsum[4][4];
    #pragma unroll
    for (int mi = 0; mi < 4; ++mi)
        #pragma unroll
        for (int r = 0; r < 4; ++r) rsum[mi][r] = 0.0f;
    float csum[4][4];   // [tile][ni]
    #pragma unroll
    for (int t = 0; t < 4; ++t)
        #pragma unroll
        for (int ni = 0; ni < 4; ++ni) csum[t][ni] = 0.0f;

    #pragma unroll
    for (int t = 0; t < 4; ++t) {
        const int tj = tj0 + t;
        if (tj < 64) {
            const int gB = tj * 8 + (wn >> 4);
            const ushort* pb[4];
            #pragma unroll
            for (int ni = 0; ni < 4; ++ni)
                pb[ni] = packed + (size_t)(gB + ni) * 4096 + (size_t)lane * 8;

            f32x4 acc[4][4];
            #pragma unroll
            for (int mi = 0; mi < 4; ++mi)
                #pragma unroll
                for (int ni = 0; ni < 4; ++ni)
                    acc[mi][ni] = (f32x4){0.f, 0.f, 0.f, 0.f};

            #pragma unroll
            for (int kt = 0; kt < 8; ++kt) {
                s16x8 af[4], bfr[4];
                #pragma unroll
                for (int mi = 0; mi < 4; ++mi)
                    af[mi] = *(const s16x8*)(pa[mi] + kt * 512);
                #pragma unroll
                for (int ni = 0; ni < 4; ++ni)
                    bfr[ni] = *(const s16x8*)(pb[ni] + kt * 512);
                #pragma unroll
                for (int mi = 0; mi < 4; ++mi)
                    #pragma unroll
                    for (int ni = 0; ni < 4; ++ni)
                        acc[mi][ni] = __builtin_amdgcn_mfma_f32_16x16x32_bf16(
                            af[mi], bfr[ni], acc[mi][ni], 0, 0, 0);
            }

            const bool diag = (tj == ti);
            #pragma unroll
            for (int mi = 0; mi < 4; ++mi)
                #pragma unroll
                for (int ni = 0; ni < 4; ++ni)
                    #pragma unroll
                    for (int r = 0; r < 4; ++r) {
                        const int lr = wm + mi * 16 + q * 4 + r;
                        const int lc = wn + ni * 16 + l15;
                        float e = exp2f(acc[mi][ni][r] * TEN_LOG2E);
                        if (diag && lr == lc) e = 0.0f;   // mask self-similarity
                        rsum[mi][r] += e;
                        csum[t][ni] += e;
                    }
        }
    }

    // row sums: one reduction + atomic set for the whole strip
    #pragma unroll
    for (int mi = 0; mi < 4; ++mi)
        #pragma unroll
        for (int r = 0; r < 4; ++r) {
            float v = rsum[mi][r];
            v += __shfl_xor(v, 1, 64);
            v += __shfl_xor(v, 2, 64);
            v += __shfl_xor(v, 4, 64);
            v += __shfl_xor(v, 8, 64);
            rsum[mi][r] = v;
        }
    if (l15 == 0) {
        #pragma unroll
        for (int mi = 0; mi < 4; ++mi)
            #pragma unroll
            for (int r = 0; r < 4; ++r)
                atomicAdd(&row_s[r0 + wm + mi * 16 + q * 4 + r], rsum[mi][r]);
    }

    // col sums (symmetric contribution), per non-diagonal tile
    #pragma unroll
    for (int t = 0; t < 4; ++t) {
        const int tj = tj0 + t;
        if (tj < 64 && tj != ti) {
            #pragma unroll
            for (int ni = 0; ni < 4; ++ni) {
                float v = csum[t][ni];
                v += __shfl_xor(v, 16, 64);
                v += __shfl_xor(v, 32, 64);
                if (q == 0)
                    atomicAdd(&row_s[tj * 128 + wn + ni * 16 + l15], v);
            }
        }
    }
}

// ---------------- Kernel 3: finalize — pos dot-products + log + reduce ---------------
// 8 blocks x 256 threads. pos[i] = 10*dot(pn_i, pn_{i+4096}) recomputed from packed
// (sum over i uses pos symmetry: total_pos = 2 * sum_{i<4096}). Also sum of log(row_s).
__global__ __launch_bounds__(256) void finalize_kernel(
    const ushort* __restrict__ packed, const float* __restrict__ row_s,
    float* __restrict__ out)
{
    const int tid = threadIdx.x;
    const int b   = blockIdx.x;
    const int w   = tid >> 6;
    const int lane = tid & 63;

    // log part: 2048 float4 across 8 blocks
    float4 s = ((const float4*)row_s)[b * 256 + tid];
    float local = __logf(s.x) + __logf(s.y) + __logf(s.z) + __logf(s.w);

    // pos part: groups 0..255 pair with groups 256..511; 32 groups/block, 8/wave
    #pragma unroll
    for (int gg = 0; gg < 8; ++gg) {
        const int g = b * 32 + w * 8 + gg;
        float dot = 0.0f;
        #pragma unroll
        for (int kt = 0; kt < 8; ++kt) {
            s16x8 fa = *(const s16x8*)(packed + ((size_t)(g * 8 + kt) * 64 + lane) * 8);
            s16x8 fb = *(const s16x8*)(packed + ((size_t)((g + 256) * 8 + kt) * 64 + lane) * 8);
            #pragma unroll
            for (int j = 0; j < 8; ++j)
                dot += bf2f((ushort)fa[j]) * bf2f((ushort)fb[j]);
        }
        dot += __shfl_xor(dot, 16, 64);
        dot += __shfl_xor(dot, 32, 64);
        if (lane < 16) local -= 20.0f * dot;   // 2 rows x 10*cos, counted once
    }

    #pragma unroll
    for (int off = 32; off > 0; off >>= 1) local += __shfl_xor(local, off, 64);
    __shared__ float red[4];
    if ((tid & 63) == 0) red[tid >> 6] = local;
    __syncthreads();
    if (tid == 0)
        atomicAdd(out, (red[0] + red[1] + red[2] + red[3]) * (1.0f / 8192.0f));
}

// ---------------- Launch ----------------
extern "C" void kernel_launch(void* const* d_in, const int* in_sizes, int n_in,
                              void* d_out, int out_size, void* d_ws, size_t ws_size,
                              hipStream_t stream)
{
    const float* zi = (const float*)d_in[0];
    const float* zj = (const float*)d_in[1];

    ushort* packed = (ushort*)d_ws;                       // 4 MB fragment-order bf16
    float* row_s   = (float*)((char*)d_ws + (4u << 20));  // 8192 fp32
    float* out     = (float*)d_out;

    hipLaunchKernelGGL(normalize_pack_kernel, dim3(512), dim3(256), 0, stream,
                       zi, zj, packed, row_s, out);
    hipLaunchKernelGGL(simexp_kernel, dim3(16, 64), dim3(256), 0, stream,
                       packed, row_s);
    hipLaunchKernelGGL(finalize_kernel, dim3(8), dim3(256), 0, stream,
                       packed, row_s, out);
}

// Round 8
// 118.736 us; speedup vs baseline: 1.1114x; 1.1114x over previous
//
#include <hip/hip_runtime.h>
#include <hip/hip_bf16.h>
#include <stdint.h>

#define AS1 __attribute__((address_space(1)))
#define AS3 __attribute__((address_space(3)))

typedef short s16x8 __attribute__((ext_vector_type(8)));
typedef float f32x4 __attribute__((ext_vector_type(4)));
typedef unsigned int u32;

static constexpr int DDIM = 256;
static constexpr float TEN_LOG2E = 14.4269504088896340736f; // 10 * log2(e)

__device__ __forceinline__ float bf2f(ushort u) {
    return __builtin_bit_cast(float, (uint32_t)u << 16);
}

// ---------------- Kernel 1: normalize + pack into MFMA-fragment order ----------------
// 512 blocks x 256 threads; block g handles rows [16g, 16g+16). packed layout:
// packed[((g*8 + kt)*64 + lane)*8 .. +8] = bf16 P[16g + (lane&15)][kt*32 + (lane>>4)*8 ..]
// Each (group, kt) fragment is a contiguous 1KB block in exact lane order.
// Also zero-inits row_s[8192] (blocks 0..7) and out[0] (block 0).
__global__ __launch_bounds__(256) void normalize_pack_kernel(
    const float* __restrict__ zi, const float* __restrict__ zj,
    ushort* __restrict__ packed, float* __restrict__ row_s, float* __restrict__ out)
{
    __shared__ ushort lds[16 * 256];

    if (blockIdx.x < 8) {
        ((float4*)row_s)[blockIdx.x * 256 + threadIdx.x] = (float4){0.f, 0.f, 0.f, 0.f};
        if (blockIdx.x == 0 && threadIdx.x == 0) out[0] = 0.0f;
    }

    const int t = threadIdx.x;
    const int r = t >> 4;            // 0..15: row within group
    const int c = t & 15;            // 16 threads per row
    const int row = blockIdx.x * 16 + r;
    const float* src = (row < 4096) ? (zi + (size_t)row * DDIM)
                                    : (zj + (size_t)(row - 4096) * DDIM);
    float4 v[4];
    #pragma unroll
    for (int j = 0; j < 4; ++j) v[j] = ((const float4*)src)[c + j * 16];

    float ss = 0.0f;
    #pragma unroll
    for (int j = 0; j < 4; ++j)
        ss += v[j].x * v[j].x + v[j].y * v[j].y + v[j].z * v[j].z + v[j].w * v[j].w;
    ss += __shfl_xor(ss, 1, 64);
    ss += __shfl_xor(ss, 2, 64);
    ss += __shfl_xor(ss, 4, 64);
    ss += __shfl_xor(ss, 8, 64);
    const float inv = 1.0f / fmaxf(sqrtf(ss), 1e-8f);

    #pragma unroll
    for (int j = 0; j < 4; ++j) {
        ushort4 o;
        o.x = __builtin_bit_cast(unsigned short, __float2bfloat16(v[j].x * inv));
        o.y = __builtin_bit_cast(unsigned short, __float2bfloat16(v[j].y * inv));
        o.z = __builtin_bit_cast(unsigned short, __float2bfloat16(v[j].z * inv));
        o.w = __builtin_bit_cast(unsigned short, __float2bfloat16(v[j].w * inv));
        *(ushort4*)(lds + r * 256 + (c + j * 16) * 4) = o;
    }
    __syncthreads();

    #pragma unroll
    for (int h = 0; h < 2; ++h) {
        const int idx  = h * 256 + t;
        const int kt   = idx >> 6;
        const int lane = idx & 63;
        const int q    = lane >> 4;
        const int l15  = lane & 15;
        s16x8 frag = *(const s16x8*)(lds + l15 * 256 + kt * 32 + q * 8);
        ((s16x8*)packed)[(size_t)(blockIdx.x * 8 + kt) * 64 + lane] = frag;
    }
}

// ---------------- Kernel 2: upper-triangle tiles, LDS-staged packed fragments --------
// 2080 blocks = 64*65/2 tiles of 128x128; 4 waves, each a 64x64 sub-tile (16x16x32
// MFMA, 4x4 frags). K=256 in 4 phases of 64: per phase each wave stages 8x 1KB
// fragment-blocks via global_load_lds(16B) (fully coalesced, conflict-free identity
// layout in LDS), then 16 ds_read_b128 + 32 MFMA. Row sums in registers; col sums via
// symmetry (atomics). Diagonal masked on diag tiles; pos handled in finalize.
__global__ __launch_bounds__(256) void simexp_kernel(
    const ushort* __restrict__ packed,
    float* __restrict__ row_s)
{
    __shared__ __align__(16) ushort ldsA[8192];   // 8 groups x 2 kt x 512
    __shared__ __align__(16) ushort ldsB[8192];

    const int tid  = threadIdx.x;
    const int w    = tid >> 6;
    const int lane = tid & 63;
    const int q    = lane >> 4;
    const int l15  = lane & 15;
    const int wm   = (w >> 1) * 64;  // wave row offset in tile
    const int wn   = (w & 1) * 64;   // wave col offset
    const int wgA  = (w >> 1) * 4;   // wave's first A group (of 8 in panel)
    const int wgB  = (w & 1) * 4;    // wave's first B group

    // ---- upper-triangle decode: block b -> (ti, tj), ti <= tj ----
    const int b = blockIdx.x;
    int ti = (int)(64.5f - sqrtf(64.5f * 64.5f - 2.0f * (float)b));
    while ((ti + 1) * 64 - ((ti + 1) * ti) / 2 <= b) ++ti;
    while (ti * 64 - (ti * (ti - 1)) / 2 > b) --ti;
    const int tj = ti + (b - (ti * 64 - (ti * (ti - 1)) / 2));
    const bool diag = (ti == tj);
    const int giA = ti * 8;          // first group of A panel
    const int giB = tj * 8;

    f32x4 acc[4][4];
    #pragma unroll
    for (int mi = 0; mi < 4; ++mi)
        #pragma unroll
        for (int ni = 0; ni < 4; ++ni)
            acc[mi][ni] = (f32x4){0.f, 0.f, 0.f, 0.f};

    #pragma unroll
    for (int ph = 0; ph < 4; ++ph) {
        if (ph) __syncthreads();     // previous phase's compute done before overwrite

        // stage this phase's K=64 slab: 16 A-blocks + 16 B-blocks of 1KB; 8 per wave
        #pragma unroll
        for (int i = 0; i < 4; ++i) {
            const int idx = w * 4 + i;          // 0..15
            const int g   = idx >> 1;           // group within panel
            const int kk  = idx & 1;
            const int kt  = ph * 2 + kk;
            const ushort* ga = packed + ((size_t)((giA + g) * 8 + kt)) * 512 + lane * 8;
            const ushort* gb = packed + ((size_t)((giB + g) * 8 + kt)) * 512 + lane * 8;
            __builtin_amdgcn_global_load_lds((const AS1 u32*)ga,
                                             (AS3 u32*)(ldsA + (g * 2 + kk) * 512), 16, 0, 0);
            __builtin_amdgcn_global_load_lds((const AS1 u32*)gb,
                                             (AS3 u32*)(ldsB + (g * 2 + kk) * 512), 16, 0, 0);
        }
        __syncthreads();

        // compute: 2 kt-steps, fragments from LDS (identity layout, base + lane*16)
        #pragma unroll
        for (int kk = 0; kk < 2; ++kk) {
            s16x8 af[4], bfr[4];
            #pragma unroll
            for (int mi = 0; mi < 4; ++mi)
                af[mi] = *(const s16x8*)(ldsA + ((wgA + mi) * 2 + kk) * 512 + lane * 8);
            #pragma unroll
            for (int ni = 0; ni < 4; ++ni)
                bfr[ni] = *(const s16x8*)(ldsB + ((wgB + ni) * 2 + kk) * 512 + lane * 8);
            #pragma unroll
            for (int mi = 0; mi < 4; ++mi)
                #pragma unroll
                for (int ni = 0; ni < 4; ++ni)
                    acc[mi][ni] = __builtin_amdgcn_mfma_f32_16x16x32_bf16(
                        af[mi], bfr[ni], acc[mi][ni], 0, 0, 0);
        }
    }

    // ---- epilogue: exp, diag mask, row+col sums (C/D: col=l15, row=q*4+r) ----
    float rsum[4][4];
    float csum[4] = {0.f, 0.f, 0.f, 0.f};
    #pragma unroll
    for (int mi = 0; mi < 4; ++mi)
        #pragma unroll
        for (int r = 0; r < 4; ++r) rsum[mi][r] = 0.0f;

    #pragma unroll
    for (int mi = 0; mi < 4; ++mi)
        #pragma unroll
        for (int ni = 0; ni < 4; ++ni)
            #pragma unroll
            for (int r = 0; r < 4; ++r) {
                const int lr = wm + mi * 16 + q * 4 + r;
                const int lc = wn + ni * 16 + l15;
                float e = exp2f(acc[mi][ni][r] * TEN_LOG2E);
                if (diag && lr == lc) e = 0.0f;          // mask self-similarity
                rsum[mi][r] += e;
                csum[ni]    += e;
            }

    #pragma unroll
    for (int mi = 0; mi < 4; ++mi)
        #pragma unroll
        for (int r = 0; r < 4; ++r) {
            float v = rsum[mi][r];
            v += __shfl_xor(v, 1, 64);
            v += __shfl_xor(v, 2, 64);
            v += __shfl_xor(v, 4, 64);
            v += __shfl_xor(v, 8, 64);
            rsum[mi][r] = v;
        }
    if (l15 == 0) {
        #pragma unroll
        for (int mi = 0; mi < 4; ++mi)
            #pragma unroll
            for (int r = 0; r < 4; ++r)
                atomicAdd(&row_s[ti * 128 + wm + mi * 16 + q * 4 + r], rsum[mi][r]);
    }

    if (!diag) {   // symmetric contribution to column rows
        #pragma unroll
        for (int ni = 0; ni < 4; ++ni) {
            float v = csum[ni];
            v += __shfl_xor(v, 16, 64);
            v += __shfl_xor(v, 32, 64);
            if (q == 0)
                atomicAdd(&row_s[tj * 128 + wn + ni * 16 + l15], v);
        }
    }
}

// ---------------- Kernel 3: finalize — pos dot-products + log + reduce ---------------
// 8 blocks x 256 threads. pos[i] = 10*dot(pn_i, pn_{i+4096}) recomputed from packed;
// sum uses pos symmetry (row i and i+4096 share the same pos value).
__global__ __launch_bounds__(256) void finalize_kernel(
    const ushort* __restrict__ packed, const float* __restrict__ row_s,
    float* __restrict__ out)
{
    const int tid = threadIdx.x;
    const int b   = blockIdx.x;
    const int w   = tid >> 6;
    const int lane = tid & 63;

    float4 s = ((const float4*)row_s)[b * 256 + tid];
    float local = __logf(s.x) + __logf(s.y) + __logf(s.z) + __logf(s.w);

    #pragma unroll
    for (int gg = 0; gg < 8; ++gg) {
        const int g = b * 32 + w * 8 + gg;
        float dot = 0.0f;
        #pragma unroll
        for (int kt = 0; kt < 8; ++kt) {
            s16x8 fa = *(const s16x8*)(packed + ((size_t)(g * 8 + kt) * 64 + lane) * 8);
            s16x8 fb = *(const s16x8*)(packed + ((size_t)((g + 256) * 8 + kt) * 64 + lane) * 8);
            #pragma unroll
            for (int j = 0; j < 8; ++j)
                dot += bf2f((ushort)fa[j]) * bf2f((ushort)fb[j]);
        }
        dot += __shfl_xor(dot, 16, 64);
        dot += __shfl_xor(dot, 32, 64);
        if (lane < 16) local -= 20.0f * dot;   // 2 rows x 10*cos, counted once
    }

    #pragma unroll
    for (int off = 32; off > 0; off >>= 1) local += __shfl_xor(local, off, 64);
    __shared__ float red[4];
    if ((tid & 63) == 0) red[tid >> 6] = local;
    __syncthreads();
    if (tid == 0)
        atomicAdd(out, (red[0] + red[1] + red[2] + red[3]) * (1.0f / 8192.0f));
}

// ---------------- Launch ----------------
extern "C" void kernel_launch(void* const* d_in, const int* in_sizes, int n_in,
                              void* d_out, int out_size, void* d_ws, size_t ws_size,
                              hipStream_t stream)
{
    const float* zi = (const float*)d_in[0];
    const float* zj = (const float*)d_in[1];

    ushort* packed = (ushort*)d_ws;                       // 4 MB fragment-order bf16
    float* row_s   = (float*)((char*)d_ws + (4u << 20));  // 8192 fp32
    float* out     = (float*)d_out;

    hipLaunchKernelGGL(normalize_pack_kernel, dim3(512), dim3(256), 0, stream,
                       zi, zj, packed, row_s, out);
    hipLaunchKernelGGL(simexp_kernel, dim3(2080), dim3(256), 0, stream,
                       packed, row_s);
    hipLaunchKernelGGL(finalize_kernel, dim3(8), dim3(256), 0, stream,
                       packed, row_s, out);
}